// Round 2
// baseline (300.617 us; speedup 1.0000x reference)
//
#include <hip/hip_runtime.h>

#define NRT 21
#define NRIG 8
#define NATOM 24
#define BLK 256

struct Op { float r[3][3]; float t[3]; };

// D = X o Y : D.R = X.R @ Y.R ; D.t = X.R @ Y.t + X.t   (D must not alias X or Y)
__device__ __forceinline__ void combine(const Op& X, const Op& Y, Op& D) {
#pragma unroll
    for (int i = 0; i < 3; ++i) {
#pragma unroll
        for (int j = 0; j < 3; ++j)
            D.r[i][j] = X.r[i][0]*Y.r[0][j] + X.r[i][1]*Y.r[1][j] + X.r[i][2]*Y.r[2][j];
        D.t[i] = X.r[i][0]*Y.t[0] + X.r[i][1]*Y.t[1] + X.r[i][2]*Y.t[2] + X.t[i];
    }
}

// o = c ? b : a   (o may alias a; elementwise, same-index read-before-write)
__device__ __forceinline__ void mixop(const Op& a, const Op& b, bool c, Op& o) {
#pragma unroll
    for (int i = 0; i < 3; ++i) {
#pragma unroll
        for (int j = 0; j < 3; ++j) o.r[i][j] = c ? b.r[i][j] : a.r[i][j];
        o.t[i] = c ? b.t[i] : a.t[i];
    }
}

// out = opr[d], d in [0,8), via cndmask chain (no scratch, registers stay live)
__device__ __forceinline__ void select8(const Op opr[NRIG], int d, Op& out) {
    out = opr[0];
#pragma unroll
    for (int k = 1; k < NRIG; ++k) mixop(out, opr[k], d == k, out);
}

__global__ __launch_bounds__(BLK) void backbone_kernel(
    const int*   __restrict__ rtyp,   // [N]
    const float* __restrict__ bb,     // [N][4][3]
    const float* __restrict__ pos0,   // [N][3]
    const float* __restrict__ sc,     // [N][7][2]
    const float* __restrict__ tf_g,   // [21][8][4][3]
    const float* __restrict__ rg_g,   // [21][24][3]
    const int*   __restrict__ td_g,   // [21][8]
    const int*   __restrict__ rd_g,   // [21][24]
    float* __restrict__ out,          // [N*24*3] then [N*4*3]
    int N)
{
    // Transposed tables in LDS: [component][restype] -> wave-gathers hit 21
    // consecutive addresses (conflict-free, mostly broadcast)
    __shared__ float s_tf[96 * NRT];
    __shared__ float s_rg[72 * NRT];
    __shared__ int   s_td[NRIG * NRT];
    __shared__ int   s_rd[NATOM * NRT];

    for (int i = threadIdx.x; i < 96 * NRT; i += BLK) {
        int rt = i / 96, k = i - rt * 96;
        s_tf[k * NRT + rt] = tf_g[i];
    }
    for (int i = threadIdx.x; i < 72 * NRT; i += BLK) {
        int rt = i / 72, k = i - rt * 72;
        s_rg[k * NRT + rt] = rg_g[i];
    }
    for (int i = threadIdx.x; i < NRIG * NRT; i += BLK) {
        int rt = i / NRIG, k = i - rt * NRIG;
        s_td[k * NRT + rt] = td_g[i];
    }
    for (int i = threadIdx.x; i < NATOM * NRT; i += BLK) {
        int rt = i / NATOM, k = i - rt * NATOM;
        s_rd[k * NRT + rt] = rd_g[i];
    }
    __syncthreads();

    int n = blockIdx.x * BLK + threadIdx.x;
    if (n >= N) return;
    int rt = rtyp[n];

    // bb: 12 floats, byte offset 48n -> 16B aligned -> 3x float4
    const float4* bb4 = (const float4*)(bb + (size_t)n * 12);
    float4 b0 = bb4[0], b1 = bb4[1], b2 = bb4[2];
    const float* pp = pos0 + (size_t)n * 3;
    float p0 = pp[0], p1 = pp[1], p2 = pp[2];

    // sc: 7 (c,s) float pairs, byte offset 56n -> 8B aligned -> float2
    const float2* sc2 = (const float2*)(sc + (size_t)n * 14);
    float2 cs[7];
#pragma unroll
    for (int i = 0; i < 7; ++i) cs[i] = sc2[i];

    Op opr[NRIG];

    // opr[0] = T0 o opr0,  opr0 = [bb rows 0..2 ; bb row3 + pos0]
    {
        Op X;
#pragma unroll
        for (int r = 0; r < 3; ++r)
#pragma unroll
            for (int c = 0; c < 3; ++c)
                X.r[r][c] = s_tf[(r * 3 + c) * NRT + rt];
#pragma unroll
        for (int c = 0; c < 3; ++c) X.t[c] = s_tf[(9 + c) * NRT + rt];
        Op Y;
        Y.r[0][0] = b0.x; Y.r[0][1] = b0.y; Y.r[0][2] = b0.z;
        Y.r[1][0] = b0.w; Y.r[1][1] = b1.x; Y.r[1][2] = b1.y;
        Y.r[2][0] = b1.z; Y.r[2][1] = b1.w; Y.r[2][2] = b2.x;
        Y.t[0] = b2.y + p0; Y.t[1] = b2.z + p1; Y.t[2] = b2.w + p2;
        combine(X, Y, opr[0]);
    }

    // opr[i] = T_i o rotX(c_i, s_i): exploit rotX structure (no full matmul)
    // rotX rows: (1,0,0),(0,c,-s),(0,s,c),(0,0,0)
#pragma unroll
    for (int i = 1; i < NRIG; ++i) {
        Op X;
#pragma unroll
        for (int r = 0; r < 3; ++r)
#pragma unroll
            for (int c = 0; c < 3; ++c)
                X.r[r][c] = s_tf[(i * 12 + r * 3 + c) * NRT + rt];
#pragma unroll
        for (int c = 0; c < 3; ++c) X.t[c] = s_tf[(i * 12 + 9 + c) * NRT + rt];
        float cv = cs[i - 1].x;
        float sv = cs[i - 1].y;
#pragma unroll
        for (int r = 0; r < 3; ++r) {
            opr[i].r[r][0] = X.r[r][0];
            opr[i].r[r][1] = X.r[r][1] * cv + X.r[r][2] * sv;
            opr[i].r[r][2] = X.r[r][2] * cv - X.r[r][1] * sv;
            opr[i].t[r]    = X.t[r];
        }
    }

    // torsion dependency chain: opr[i] = opr[dep(i)] o opr[i], dep(i) < i
#pragma unroll
    for (int i = 1; i < NRIG; ++i) {
        int d = s_td[i * NRT + rt];
        Op prev = opr[0];
#pragma unroll
        for (int k = 1; k < NRIG; ++k) {
            if (k < i) mixop(prev, opr[k], d == k, prev);
        }
        Op res;
        combine(prev, opr[i], res);
        opr[i] = res;
    }

    // atoms: out[n][a] = opr[rdep(a)].R @ rigids[a] + opr[rdep(a)].t
    float* outR = out + (size_t)n * 72;
#pragma unroll
    for (int ch = 0; ch < 6; ++ch) {   // 6 chunks of 4 atoms -> 12 floats -> 3x float4
        float w[12];
#pragma unroll
        for (int q = 0; q < 4; ++q) {
            int a = ch * 4 + q;
            int d = s_rd[a * NRT + rt];
            Op T;
            select8(opr, d, T);
            float vx = s_rg[(a * 3 + 0) * NRT + rt];
            float vy = s_rg[(a * 3 + 1) * NRT + rt];
            float vz = s_rg[(a * 3 + 2) * NRT + rt];
            w[q * 3 + 0] = T.r[0][0] * vx + T.r[0][1] * vy + T.r[0][2] * vz + T.t[0];
            w[q * 3 + 1] = T.r[1][0] * vx + T.r[1][1] * vy + T.r[1][2] * vz + T.t[1];
            w[q * 3 + 2] = T.r[2][0] * vx + T.r[2][1] * vy + T.r[2][2] * vz + T.t[2];
        }
        float4* dst = (float4*)(outR + ch * 12);  // byte 288n + 48ch: 16B aligned
        dst[0] = make_float4(w[0], w[1], w[2],  w[3]);
        dst[1] = make_float4(w[4], w[5], w[6],  w[7]);
        dst[2] = make_float4(w[8], w[9], w[10], w[11]);
    }

    // second output: opr[:,0] flat (r00..r22, t0..t2), byte 48n from 16B-aligned base
    {
        float4* df = (float4*)(out + (size_t)N * 72 + (size_t)n * 12);
        df[0] = make_float4(opr[0].r[0][0], opr[0].r[0][1], opr[0].r[0][2], opr[0].r[1][0]);
        df[1] = make_float4(opr[0].r[1][1], opr[0].r[1][2], opr[0].r[2][0], opr[0].r[2][1]);
        df[2] = make_float4(opr[0].r[2][2], opr[0].t[0],    opr[0].t[1],    opr[0].t[2]);
    }
}

extern "C" void kernel_launch(void* const* d_in, const int* in_sizes, int n_in,
                              void* d_out, int out_size, void* d_ws, size_t ws_size,
                              hipStream_t stream) {
    const int*   rtyp = (const int*)d_in[0];
    const float* bb   = (const float*)d_in[1];
    const float* pos0 = (const float*)d_in[2];
    const float* sc   = (const float*)d_in[3];
    const float* tf   = (const float*)d_in[4];
    const float* rg   = (const float*)d_in[5];
    const int*   td   = (const int*)d_in[6];
    const int*   rd   = (const int*)d_in[7];
    int N = in_sizes[0];
    int grid = (N + BLK - 1) / BLK;
    backbone_kernel<<<grid, BLK, 0, stream>>>(rtyp, bb, pos0, sc, tf, rg, td, rd,
                                              (float*)d_out, N);
}

// Round 3
// 288.130 us; speedup vs baseline: 1.0433x; 1.0433x over previous
//
#include <hip/hip_runtime.h>
#include <hip/hip_fp16.h>

#define NRT 21
#define NRIG 8
#define NATOM 24
#define BLK 256

typedef unsigned int u32;
typedef unsigned char u8;

struct Op { float r[3][3]; float t[3]; };

// D = X o Y : D.R = X.R @ Y.R ; D.t = X.R @ Y.t + X.t   (D must not alias X or Y)
__device__ __forceinline__ void combine(const Op& X, const Op& Y, Op& D) {
#pragma unroll
    for (int i = 0; i < 3; ++i) {
#pragma unroll
        for (int j = 0; j < 3; ++j)
            D.r[i][j] = X.r[i][0]*Y.r[0][j] + X.r[i][1]*Y.r[1][j] + X.r[i][2]*Y.r[2][j];
        D.t[i] = X.r[i][0]*Y.t[0] + X.r[i][1]*Y.t[1] + X.r[i][2]*Y.t[2] + X.t[i];
    }
}

// o = c ? b : a (elementwise; o may alias a)
__device__ __forceinline__ void mixop(const Op& a, const Op& b, bool c, Op& o) {
#pragma unroll
    for (int i = 0; i < 3; ++i) {
#pragma unroll
        for (int j = 0; j < 3; ++j) o.r[i][j] = c ? b.r[i][j] : a.r[i][j];
        o.t[i] = c ? b.t[i] : a.t[i];
    }
}

__device__ __forceinline__ u32 pk(float a, float b) {
    __half2 h = __floats2half2_rn(a, b);
    return __builtin_bit_cast(u32, h);
}
__device__ __forceinline__ float unlo(u32 w) {
    __half2 h = __builtin_bit_cast(__half2, w); return __low2float(h);
}
__device__ __forceinline__ float unhi(u32 w) {
    __half2 h = __builtin_bit_cast(__half2, w); return __high2float(h);
}

__global__ __launch_bounds__(BLK, 2) void backbone_kernel(
    const int*   __restrict__ rtyp,   // [N]
    const float* __restrict__ bb,     // [N][4][3]
    const float* __restrict__ pos0,   // [N][3]
    const float* __restrict__ sc,     // [N][7][2]
    const float* __restrict__ tf_g,   // [21][8][4][3]
    const float* __restrict__ rg_g,   // [21][24][3]
    const int*   __restrict__ td_g,   // [21][8]
    const int*   __restrict__ rd_g,   // [21][24]
    float* __restrict__ out,          // [N*24*3] then [N*4*3]
    int N)
{
    // opr store: 8 ops x 6 packed-f16-pair words per thread, [(op*6+c)*BLK + t]
    // -> every wave access is lane-consecutive: conflict-free.
    __shared__ u32   s_opr[48 * BLK];            // 48 KB
    __shared__ float s_tf[96 * NRT];             // 8.06 KB  [component][restype]
    __shared__ float s_rg[72 * NRT];             // 6.05 KB  [component][restype]
    __shared__ u8    s_td[NRIG * NRT];           // 168 B    [rigid][restype]
    __shared__ u8    s_rd[NATOM * NRT];          // 504 B    [atom][restype]

    for (int i = threadIdx.x; i < 96 * NRT; i += BLK) {
        int rt = i / 96, k = i - rt * 96;
        s_tf[k * NRT + rt] = tf_g[i];
    }
    for (int i = threadIdx.x; i < 72 * NRT; i += BLK) {
        int rt = i / 72, k = i - rt * 72;
        s_rg[k * NRT + rt] = rg_g[i];
    }
    for (int i = threadIdx.x; i < NRIG * NRT; i += BLK) {
        int rt = i / NRIG, k = i - rt * NRIG;
        s_td[k * NRT + rt] = (u8)td_g[i];
    }
    for (int i = threadIdx.x; i < NATOM * NRT; i += BLK) {
        int rt = i / NATOM, k = i - rt * NATOM;
        s_rd[k * NRT + rt] = (u8)rd_g[i];
    }
    __syncthreads();

    int n = blockIdx.x * BLK + threadIdx.x;
    if (n >= N) return;
    int t = threadIdx.x;
    int rt = rtyp[n];

    // bb: 12 floats @48n -> 16B aligned -> 3x float4
    const float4* bb4 = (const float4*)(bb + (size_t)n * 12);
    float4 b0 = bb4[0], b1 = bb4[1], b2 = bb4[2];
    const float* pp = pos0 + (size_t)n * 3;
    float p0 = pp[0], p1 = pp[1], p2 = pp[2];

    // sc: 7 (c,s) pairs @56n -> 8B aligned float2s
    const float2* sc2 = (const float2*)(sc + (size_t)n * 14);
    float2 cs[7];
#pragma unroll
    for (int i = 0; i < 7; ++i) cs[i] = sc2[i];

    Op opr[NRIG];

    // opr[0] = T0 o [bb rows 0..2 ; bb row3 + pos0]
    {
        Op X;
#pragma unroll
        for (int r = 0; r < 3; ++r)
#pragma unroll
            for (int c = 0; c < 3; ++c)
                X.r[r][c] = s_tf[(r * 3 + c) * NRT + rt];
#pragma unroll
        for (int c = 0; c < 3; ++c) X.t[c] = s_tf[(9 + c) * NRT + rt];
        Op Y;
        Y.r[0][0] = b0.x; Y.r[0][1] = b0.y; Y.r[0][2] = b0.z;
        Y.r[1][0] = b0.w; Y.r[1][1] = b1.x; Y.r[1][2] = b1.y;
        Y.r[2][0] = b1.z; Y.r[2][1] = b1.w; Y.r[2][2] = b2.x;
        Y.t[0] = b2.y + p0; Y.t[1] = b2.z + p1; Y.t[2] = b2.w + p2;
        combine(X, Y, opr[0]);
    }

    // opr[i] = T_i o rotX(c,s); rotX rows (1,0,0),(0,c,-s),(0,s,c),(0,0,0)
#pragma unroll
    for (int i = 1; i < NRIG; ++i) {
        Op X;
#pragma unroll
        for (int r = 0; r < 3; ++r)
#pragma unroll
            for (int c = 0; c < 3; ++c)
                X.r[r][c] = s_tf[(i * 12 + r * 3 + c) * NRT + rt];
#pragma unroll
        for (int c = 0; c < 3; ++c) X.t[c] = s_tf[(i * 12 + 9 + c) * NRT + rt];
        float cv = cs[i - 1].x, sv = cs[i - 1].y;
#pragma unroll
        for (int r = 0; r < 3; ++r) {
            opr[i].r[r][0] = X.r[r][0];
            opr[i].r[r][1] = X.r[r][1] * cv + X.r[r][2] * sv;
            opr[i].r[r][2] = X.r[r][2] * cv - X.r[r][1] * sv;
            opr[i].t[r]    = X.t[r];
        }
    }

    // dependency chain: opr[i] = opr[dep(i)] o opr[i], dep(i) < i (register selects)
#pragma unroll
    for (int i = 1; i < NRIG; ++i) {
        int d = (int)s_td[i * NRT + rt];
        Op prev = opr[0];
#pragma unroll
        for (int k = 1; k < NRIG; ++k) {
            if (k < i) mixop(prev, opr[k], d == k, prev);
        }
        Op res;
        combine(prev, opr[i], res);
        opr[i] = res;
    }

    // dump all 8 finalized ops to LDS as packed f16 pairs (frees opr[1..7] regs)
#pragma unroll
    for (int i = 0; i < NRIG; ++i) {
        const Op& o = opr[i];
        u32* dst = s_opr + (i * 6) * BLK + t;
        dst[0 * BLK] = pk(o.r[0][0], o.r[0][1]);
        dst[1 * BLK] = pk(o.r[0][2], o.r[1][0]);
        dst[2 * BLK] = pk(o.r[1][1], o.r[1][2]);
        dst[3 * BLK] = pk(o.r[2][0], o.r[2][1]);
        dst[4 * BLK] = pk(o.r[2][2], o.t[0]);
        dst[5 * BLK] = pk(o.t[1],    o.t[2]);
    }
    // no __syncthreads needed: each thread reads back only its own slots

    // atoms: out[n][a] = opr[rdep(a)].R @ rigids[a] + opr[rdep(a)].t
    float* outR = out + (size_t)n * 72;
#pragma unroll
    for (int ch = 0; ch < 6; ++ch) {   // 4 atoms -> 12 floats -> 3x float4
        float w[12];
#pragma unroll
        for (int q = 0; q < 4; ++q) {
            int a = ch * 4 + q;
            int d = (int)s_rd[a * NRT + rt];
            const u32* src = s_opr + (d * 6) * BLK + t;
            u32 w0 = src[0 * BLK], w1 = src[1 * BLK], w2 = src[2 * BLK];
            u32 w3 = src[3 * BLK], w4 = src[4 * BLK], w5 = src[5 * BLK];
            float r00 = unlo(w0), r01 = unhi(w0), r02 = unlo(w1);
            float r10 = unhi(w1), r11 = unlo(w2), r12 = unhi(w2);
            float r20 = unlo(w3), r21 = unhi(w3), r22 = unlo(w4);
            float t0  = unhi(w4), t1  = unlo(w5), t2  = unhi(w5);
            float vx = s_rg[(a * 3 + 0) * NRT + rt];
            float vy = s_rg[(a * 3 + 1) * NRT + rt];
            float vz = s_rg[(a * 3 + 2) * NRT + rt];
            w[q * 3 + 0] = fmaf(r00, vx, fmaf(r01, vy, fmaf(r02, vz, t0)));
            w[q * 3 + 1] = fmaf(r10, vx, fmaf(r11, vy, fmaf(r12, vz, t1)));
            w[q * 3 + 2] = fmaf(r20, vx, fmaf(r21, vy, fmaf(r22, vz, t2)));
        }
        float4* dst = (float4*)(outR + ch * 12);  // byte 288n + 48ch: 16B aligned
        dst[0] = make_float4(w[0], w[1], w[2],  w[3]);
        dst[1] = make_float4(w[4], w[5], w[6],  w[7]);
        dst[2] = make_float4(w[8], w[9], w[10], w[11]);
    }

    // second output: opr[:,0] (exact f32 from registers)
    {
        float4* df = (float4*)(out + (size_t)N * 72 + (size_t)n * 12);
        df[0] = make_float4(opr[0].r[0][0], opr[0].r[0][1], opr[0].r[0][2], opr[0].r[1][0]);
        df[1] = make_float4(opr[0].r[1][1], opr[0].r[1][2], opr[0].r[2][0], opr[0].r[2][1]);
        df[2] = make_float4(opr[0].r[2][2], opr[0].t[0],    opr[0].t[1],    opr[0].t[2]);
    }
}

extern "C" void kernel_launch(void* const* d_in, const int* in_sizes, int n_in,
                              void* d_out, int out_size, void* d_ws, size_t ws_size,
                              hipStream_t stream) {
    const int*   rtyp = (const int*)d_in[0];
    const float* bb   = (const float*)d_in[1];
    const float* pos0 = (const float*)d_in[2];
    const float* sc   = (const float*)d_in[3];
    const float* tf   = (const float*)d_in[4];
    const float* rg   = (const float*)d_in[5];
    const int*   td   = (const int*)d_in[6];
    const int*   rd   = (const int*)d_in[7];
    int N = in_sizes[0];
    int grid = (N + BLK - 1) / BLK;
    backbone_kernel<<<grid, BLK, 0, stream>>>(rtyp, bb, pos0, sc, tf, rg, td, rd,
                                              (float*)d_out, N);
}